// Round 1
// baseline (425.027 us; speedup 1.0000x reference)
//
#include <hip/hip_runtime.h>

// CentDif: 6th-order central difference along last axis + advection combine.
// u: (M, 2, L) fp32, L=2048, ghost=10 cells each side of last axis.
// out[m,0,l] = -( u1*du0 + u0*du1 )
// out[m,1,l] = -( 2*du0 + u1*du1 )
// du_c = c * (-u[l-3] + 9u[l-2] - 45u[l-1] + 45u[l+1] - 9u[l+2] + u[l+3]), 0 in ghost.

#define LDIM 2048
#define IGST 10
#define DXF  0.012f

__global__ __launch_bounds__(256) void centdif_kernel(const float* __restrict__ u,
                                                      float* __restrict__ out) {
    const int m = blockIdx.x;
    const int t = threadIdx.x;
    const int l0 = t * 8;                       // this thread's 8 contiguous l's
    const float c = 1.0f / (60.0f * DXF);

    const float* __restrict__ u0 = u + (size_t)(2 * m) * LDIM;
    const float* __restrict__ u1 = u0 + LDIM;
    float* __restrict__ o0 = out + (size_t)(2 * m) * LDIM;
    float* __restrict__ o1 = o0 + LDIM;

    // Threads 0 and 255 cover only ghost columns (l<8+? : l in [0,8) and [2040,2048),
    // all inside the ghost regions [0,10) / [2038,2048)) -> outputs are exactly 0.
    if (t == 0 || t == 255) {
        float4 z = make_float4(0.f, 0.f, 0.f, 0.f);
        ((float4*)(o0 + l0))[0] = z;
        ((float4*)(o0 + l0))[1] = z;
        ((float4*)(o1 + l0))[0] = z;
        ((float4*)(o1 + l0))[1] = z;
        return;
    }

    // Register window [l0-4, l0+12) per channel; base is 16B-aligned, in [4, 2028].
    const int base = l0 - 4;
    float a[16], b[16];
    {
        const float4* pa = (const float4*)(u0 + base);
        const float4* pb = (const float4*)(u1 + base);
#pragma unroll
        for (int i = 0; i < 4; ++i) {
            float4 va = pa[i];
            float4 vb = pb[i];
            a[4 * i + 0] = va.x; a[4 * i + 1] = va.y; a[4 * i + 2] = va.z; a[4 * i + 3] = va.w;
            b[4 * i + 0] = vb.x; b[4 * i + 1] = vb.y; b[4 * i + 2] = vb.z; b[4 * i + 3] = vb.w;
        }
    }

    float r0[8], r1[8];
#pragma unroll
    for (int k = 0; k < 8; ++k) {
        const int l = l0 + k;
        const int i = k + 4;                    // compile-time after unroll
        float d0 = (-a[i - 3] + 9.0f * a[i - 2] - 45.0f * a[i - 1]
                    + 45.0f * a[i + 1] - 9.0f * a[i + 2] + a[i + 3]) * c;
        float d1 = (-b[i - 3] + 9.0f * b[i - 2] - 45.0f * b[i - 1]
                    + 45.0f * b[i + 1] - 9.0f * b[i + 2] + b[i + 3]) * c;
        const bool interior = (l >= IGST) && (l < LDIM - IGST);
        d0 = interior ? d0 : 0.0f;
        d1 = interior ? d1 : 0.0f;
        r0[k] = -(b[i] * d0 + a[i] * d1);
        r1[k] = -(2.0f * d0 + b[i] * d1);
    }

    // Coalesced float4 stores, 2 per channel.
    ((float4*)(o0 + l0))[0] = make_float4(r0[0], r0[1], r0[2], r0[3]);
    ((float4*)(o0 + l0))[1] = make_float4(r0[4], r0[5], r0[6], r0[7]);
    ((float4*)(o1 + l0))[0] = make_float4(r1[0], r1[1], r1[2], r1[3]);
    ((float4*)(o1 + l0))[1] = make_float4(r1[4], r1[5], r1[6], r1[7]);
}

extern "C" void kernel_launch(void* const* d_in, const int* in_sizes, int n_in,
                              void* d_out, int out_size, void* d_ws, size_t ws_size,
                              hipStream_t stream) {
    const float* u = (const float*)d_in[0];
    float* out = (float*)d_out;
    const int M = in_sizes[0] / (2 * LDIM);     // 16384
    centdif_kernel<<<M, 256, 0, stream>>>(u, out);
}

// Round 2
// 417.365 us; speedup vs baseline: 1.0184x; 1.0184x over previous
//
#include <hip/hip_runtime.h>

// CentDif: 6th-order central difference along last axis + advection combine.
// u: (M, 2, L) fp32, L=2048, ghost=10 each side.
// out[m,0,l] = -( u1*du0 + u0*du1 )
// out[m,1,l] = -( 2*du0  + u1*du1 )
// du_c = c*(-u[l-3] + 9u[l-2] - 45u[l-1] + 45u[l+1] - 9u[l+2] + u[l+3]), 0 in ghost.
//
// Layout: one float4 (4 l's, both channels) per thread, lane-contiguous.
// Per-instruction lane stride = 16 B -> perfect coalescing on loads & stores.

#define LDIM 2048
#define IGST 10
#define DXF  0.012f

__global__ __launch_bounds__(256) void centdif_kernel(const float* __restrict__ u,
                                                      float* __restrict__ out) {
    const int gid = blockIdx.x * 256 + threadIdx.x;  // float4-chunk id
    const int m   = gid >> 9;                        // 512 chunks per row
    const int lc  = gid & 511;
    const int l0  = lc << 2;
    const float c = 1.0f / (60.0f * DXF);

    const float* __restrict__ u0 = u + (size_t)(2 * m) * LDIM;
    const float* __restrict__ u1 = u0 + LDIM;
    float* __restrict__ o0 = out + (size_t)(2 * m) * LDIM;
    float* __restrict__ o1 = o0 + LDIM;

    // Chunks fully inside a ghost region: write zeros, no loads.
    // (l0+3 < 10  ->  l0 in {0,4};  l0 >= 2038  ->  l0 in {2040,2044})
    if (l0 + 3 < IGST || l0 >= LDIM - IGST) {
        const float4 z = make_float4(0.f, 0.f, 0.f, 0.f);
        *(float4*)(o0 + l0) = z;
        *(float4*)(o1 + l0) = z;
        return;
    }

    // Window [l0-4, l0+8): 12 floats per channel, 3 aligned float4 loads each.
    // Safe: surviving chunks have l0 >= 8 (base >= 4) and l0 <= 2036 (top <= 2044).
    const float4* pa = (const float4*)(u0 + l0 - 4);
    const float4* pb = (const float4*)(u1 + l0 - 4);
    float4 a0 = pa[0], a1 = pa[1], a2 = pa[2];
    float4 b0 = pb[0], b1 = pb[1], b2 = pb[2];

    float a[12] = {a0.x, a0.y, a0.z, a0.w, a1.x, a1.y, a1.z, a1.w, a2.x, a2.y, a2.z, a2.w};
    float b[12] = {b0.x, b0.y, b0.z, b0.w, b1.x, b1.y, b1.z, b1.w, b2.x, b2.y, b2.z, b2.w};

    float r0[4], r1[4];
#pragma unroll
    for (int k = 0; k < 4; ++k) {
        const int i = k + 4;                         // window-local index of l0+k
        const int l = l0 + k;
        float d0 = (-a[i - 3] + 9.0f * a[i - 2] - 45.0f * a[i - 1]
                    + 45.0f * a[i + 1] - 9.0f * a[i + 2] + a[i + 3]) * c;
        float d1 = (-b[i - 3] + 9.0f * b[i - 2] - 45.0f * b[i - 1]
                    + 45.0f * b[i + 1] - 9.0f * b[i + 2] + b[i + 3]) * c;
        const bool interior = (l >= IGST) && (l < LDIM - IGST);
        d0 = interior ? d0 : 0.0f;
        d1 = interior ? d1 : 0.0f;
        r0[k] = -(b[i] * d0 + a[i] * d1);
        r1[k] = -(2.0f * d0 + b[i] * d1);
    }

    *(float4*)(o0 + l0) = make_float4(r0[0], r0[1], r0[2], r0[3]);
    *(float4*)(o1 + l0) = make_float4(r1[0], r1[1], r1[2], r1[3]);
}

extern "C" void kernel_launch(void* const* d_in, const int* in_sizes, int n_in,
                              void* d_out, int out_size, void* d_ws, size_t ws_size,
                              hipStream_t stream) {
    const float* u = (const float*)d_in[0];
    float* out = (float*)d_out;
    const int M = in_sizes[0] / (2 * LDIM);          // 16384
    const int chunks = M * (LDIM / 4);               // 8,388,608 float4 chunks
    centdif_kernel<<<chunks / 256, 256, 0, stream>>>(u, out);
}